// Round 5
// baseline (338.190 us; speedup 1.0000x reference)
//
#include <hip/hip_runtime.h>

// Correlation1D on MI355X (gfx950), round 5.
// out[b,d,h,w] = (1/256) * sum_c in1[b,c,h,w] * in2[b,c,h,w+d-40]
// B=8 C=256 H=96 W=192 D=81 PAD=40.
//
// R5: 768 full-row blocks, but LDS holds ONLY the B (in2) chunk (24.8 KB,
// width=16 global_load_lds, 16B-aligned parity-offset rows) -> 4-5 blocks/CU
// instead of 3. A (in1) fragments are lane-private: loaded straight from
// global (read-once, coalesced), no LDS, no barrier dependency. KC=32 keeps
// the round-verified 16x16x32 MFMA band + epilogue (3 phases x 27 d-rows).

typedef __attribute__((ext_vector_type(8))) short short8;     // 8 bf16
typedef __attribute__((ext_vector_type(4))) float float4v;

__device__ __forceinline__ unsigned short f2bf(float f) {
  // round-to-nearest-even fp32 -> bf16
  unsigned int u = __float_as_uint(f);
  return (unsigned short)((u + 0x7FFFu + ((u >> 16) & 1u)) >> 16);
}

__device__ __forceinline__ void glds16(const float* g, float* l) {
  __builtin_amdgcn_global_load_lds(
      (const __attribute__((address_space(1))) void*)g,
      (__attribute__((address_space(3))) void*)l, 16, 0, 0);
}

// B LDS row base for k-row (in floats): 194 floats data+pad, +2 on odd rows
// so every row base is 16B-aligned while 8*stride % 32 == 16 keeps the
// strided b32 fragment reads at free 2-way bank aliasing.
__device__ __forceinline__ int rbB(int k) { return 194 * k + 2 * (k & 1); }

__global__ __launch_bounds__(256, 4) void corr1d_kernel(
    const float* __restrict__ in1, const float* __restrict__ in2,
    float* __restrict__ out) {
  constexpr int W = 192, H = 96, C = 256, D = 81;
  constexpr int HW = H * W;          // c-stride in elements
  constexpr int KC = 32;             // channels per chunk
  constexpr int ES = 196;            // epilogue row stride (16B-aligned)

  // B stage: rbB(31)+194 = 6216 floats = 24864 B. Epilogue E[27][196] =
  // 21168 B overlays it. ~25 KB/block -> LDS allows 6 blocks/CU.
  __shared__ __align__(16) float smem[6216];
  float* Bs = smem;
  float* E  = smem;

  const int bh = blockIdx.x;
  const int b = bh / H, h = bh % H;
  const int tid = threadIdx.x;
  const int lane = tid & 63;
  const int wv = tid >> 6;           // wave 0..3, owns w-tiles 3wv..3wv+2
  const int l15 = lane & 15, lq = lane >> 4;
  const int base = (b * C * H + h) * W;

  float4v acc[3][6];
#pragma unroll
  for (int i = 0; i < 3; ++i)
#pragma unroll
    for (int jj = 0; jj < 6; ++jj) acc[i][jj] = (float4v){0.f, 0.f, 0.f, 0.f};

  const float* a_col = in1 + base + 48 * wv + l15;   // + 16*i + c*HW

  for (int m = 0; m < C / KC; ++m) {
    const int c0 = KC * m;
    __syncthreads();                 // previous chunk's B readers done

    // ---- B stage: wave wv loads k rows 8wv..8wv+7, one width-16 async
    // instruction per row (lanes 0..47 cover 768 B). Zero result VGPRs.
#pragma unroll
    for (int r = 0; r < 8; ++r) {
      const int k = 8 * wv + r;
      if (lane < 48)
        glds16(in2 + base + (c0 + k) * HW + 4 * lane, Bs + rbB(k));
    }

    // ---- A fragments straight from global (lane-private, read-once)
    float a_raw[3][8];
#pragma unroll
    for (int i = 0; i < 3; ++i)
#pragma unroll
      for (int t = 0; t < 8; ++t)
        a_raw[i][t] = a_col[(c0 + 8 * lq + t) * HW + 16 * i];
    short8 af[3];
#pragma unroll
    for (int i = 0; i < 3; ++i) {
      unsigned short o[8];
#pragma unroll
      for (int t = 0; t < 8; ++t) o[t] = f2bf(a_raw[i][t]);
      af[i] = *(const short8*)o;
    }

    __syncthreads();                 // B chunk visible (vmcnt drain folded in)

    // ---- banded MFMA: 8 aligned j-tiles, band of 6 per w-tile
#pragma unroll
    for (int jt = 0; jt < 8; ++jt) {
      const int j = 16 * (3 * wv + jt) + l15;     // padded j coord
      const bool ok = (j >= 40) && (j < 232);     // in2 col = j-40
      const int col = ok ? (j - 40) : 0;
      unsigned short o[8];
#pragma unroll
      for (int t = 0; t < 8; ++t) {
        float v = ok ? Bs[rbB(8 * lq + t) + col] : 0.0f;
        o[t] = f2bf(v);
      }
      short8 bfr = *(const short8*)o;
#pragma unroll
      for (int i = 0; i < 3; ++i) {
        const int jj = jt - i;                    // compile-time after unroll
        if (jj >= 0 && jj < 6)
          acc[i][jj] = __builtin_amdgcn_mfma_f32_16x16x32_bf16(
              af[i], bfr, acc[i][jj], 0, 0, 0);
      }
    }
  }

  // ---- epilogue: D layout col(j)=l15, row(w)=4lq+r -> d = 16jj+l15-4lq-r.
  // Three d-phases (27 rows each) through LDS overlay; float4 row stores.
  const float scale = 1.0f / 256.0f;
#pragma unroll
  for (int p = 0; p < 3; ++p) {
    const int dlo = 27 * p;
    __syncthreads();                 // stage buffer / previous E free
#pragma unroll
    for (int i = 0; i < 3; ++i)
#pragma unroll
      for (int jj = 0; jj < 6; ++jj)
#pragma unroll
        for (int r = 0; r < 4; ++r) {
          const int d = 16 * jj + l15 - 4 * lq - r;
          const int w = 48 * wv + 16 * i + 4 * lq + r;
          if (d >= dlo && d < dlo + 27)
            E[(d - dlo) * ES + w] = acc[i][jj][r] * scale;
        }
    __syncthreads();
    for (int t = tid; t < 27 * 48; t += 256) {
      const int dr = t / 48, g = t % 48;
      float4v val = *(const float4v*)(E + dr * ES + 4 * g);
      *(float4v*)(out + ((b * D + dlo + dr) * H + h) * W + 4 * g) = val;
    }
  }
}

extern "C" void kernel_launch(void* const* d_in, const int* in_sizes, int n_in,
                              void* d_out, int out_size, void* d_ws, size_t ws_size,
                              hipStream_t stream) {
  const float* in1 = (const float*)d_in[0];
  const float* in2 = (const float*)d_in[1];
  float* out = (float*)d_out;
  (void)in_sizes; (void)n_in; (void)out_size; (void)d_ws; (void)ws_size;
  corr1d_kernel<<<dim3(768), dim3(256), 0, stream>>>(in1, in2, out);
}